// Round 4
// baseline (630.492 us; speedup 1.0000x reference)
//
#include <hip/hip_runtime.h>

#define BB  256
#define TT  500
#define ENC 700
#define ENC_PAD 704   // rows 700..703 of w1t are zeros (gather padding target)
#define HID 128
#define LMAX 80       // per-row index-list capacity; max n ~ 70 (35 + 6 sigma)

// ---------------------------------------------------------------------------
// Kernel 1: transpose w1 (HID, ENC) -> w1t (ENC_PAD, HID); pad rows = 0
// ---------------------------------------------------------------------------
__global__ __launch_bounds__(128) void transpose_w1_kernel(const float* __restrict__ w1,
                                                           float* __restrict__ w1t) {
    int c = blockIdx.x;      // 0..ENC_PAD-1
    int h = threadIdx.x;     // 0..HID-1
    w1t[c * HID + h] = (c < ENC) ? w1[h * ENC + c] : 0.0f;
}

// ---------------------------------------------------------------------------
// Kernel 2a: compress x rows into ascending column-index lists (ushort),
// padded to LMAX with the zero column (ENC). One wave per row.
// Same ballot structure as the round-3 proven-exact compaction.
// ---------------------------------------------------------------------------
__global__ __launch_bounds__(256) void compress_kernel(const float* __restrict__ x,
                                                       ushort* __restrict__ lists,
                                                       int* __restrict__ ncnt) {
    __shared__ ushort lds[4][LMAX];
    const int lane = threadIdx.x & 63;
    const int w = threadIdx.x >> 6;
    const int r = blockIdx.x * 4 + w;                 // row = b*TT + t
    const float* xrow = x + (size_t)r * ENC;
    const unsigned long long lt = (1ull << lane) - 1ull;

    float xv[11];
    #pragma unroll
    for (int k = 0; k < 11; ++k) {
        int c = k * 64 + lane;
        xv[k] = (c < ENC) ? xrow[c] : 0.0f;
    }
    int base = 0;
    #pragma unroll
    for (int k = 0; k < 11; ++k) {
        bool act = (xv[k] != 0.0f);
        unsigned long long m = __ballot(act);
        if (act) {
            int pos = base + (int)__popcll(m & lt);
            if (pos < LMAX) lds[w][pos] = (ushort)(k * 64 + lane);
        }
        base += (int)__popcll(m);
    }
    int n = (base < LMAX) ? base : LMAX;
    for (int p = n + lane; p < LMAX; p += 64) lds[w][p] = (ushort)ENC;  // zero-col pad
    if (lane == 0) ncnt[r] = n;
    // coalesced flush: 40 uints per row (wave-local LDS dep -> compiler lgkmcnt)
    if (lane < LMAX / 2)
        ((uint*)lists)[(size_t)r * (LMAX / 2) + lane] =
            ((const uint*)lds)[w * (LMAX / 2) + lane];
}

// ---------------------------------------------------------------------------
// Kernel 2b: gather. Each block owns a 16-channel slice of w1t staged in LDS
// (stride 18 dwords: 8B-aligned float2, bank rotation) and 512 consecutive
// rows. Inner loop: 8 indices per b128 broadcast read, 8 ds_read_b64 column
// reads, strictly-ascending ordered adds per channel (bit-exact).
// LDS: 50688 + 10240 + 256 = 61 KB -> 2 blocks/CU (8 waves).
// ---------------------------------------------------------------------------
#define GROWS 512
#define GRP   64
#define QCH   16
#define WST   18

__global__ __launch_bounds__(256) void gather_kernel(const ushort* __restrict__ lists,
                                                     const int* __restrict__ ncnt,
                                                     const float* __restrict__ w1t,
                                                     float* __restrict__ h) {
    __shared__ float  w1q[ENC_PAD * WST];   // 50688 B
    __shared__ ushort ll[GRP * LMAX];       // 10240 B
    __shared__ int    nb[GRP];

    const int tid = threadIdx.x;
    const int lane = tid & 63;
    const int w = tid >> 6;
    const int q = blockIdx.y;               // channel-eighth 0..7
    const int r0b = blockIdx.x * GROWS;

    // stage the 16-channel slice of w1t (incl. zero rows 700..703)
    for (int i = tid; i < ENC_PAD * QCH; i += 256) {
        int c = i >> 4, ch = i & 15;
        w1q[c * WST + ch] = w1t[c * HID + q * QCH + ch];
    }

    const int chl = (lane & 7) * 2;         // 2 channels per lane
    const int rw  = lane >> 3;              // row-in-wave 0..7

    for (int g = 0; g < GROWS / GRP; ++g) {
        const int r0 = r0b + g * GRP;
        __syncthreads();                    // prev group's reads done; w1q visible
        {   // stage 64 rows' lists: 2560 uints, coalesced
            const uint* src = (const uint*)lists + (size_t)r0 * (LMAX / 2);
            uint* dst = (uint*)ll;
            #pragma unroll
            for (int k = 0; k < 10; ++k) dst[tid + k * 256] = src[tid + k * 256];
        }
        if (tid < GRP) nb[tid] = ncnt[r0 + tid];
        __syncthreads();

        #pragma unroll
        for (int p = 0; p < 2; ++p) {       // 2 passes x (4 waves x 8 rows)
            const int rl = p * 32 + w * 8 + rw;
            int n = nb[rl];
            n = max(n, __shfl_xor(n, 8));
            n = max(n, __shfl_xor(n, 16));
            n = max(n, __shfl_xor(n, 32));
            const int jmax = (n + 7) & ~7;

            float a0 = 0.f, a1 = 0.f;
            for (int j = 0; j < jmax; j += 8) {
                uint4 iv = *(const uint4*)&ll[rl * LMAX + j];   // 8 idx, broadcast
                int c0 = (int)(iv.x & 0xffff), c1 = (int)(iv.x >> 16);
                int c2 = (int)(iv.y & 0xffff), c3 = (int)(iv.y >> 16);
                int c4 = (int)(iv.z & 0xffff), c5 = (int)(iv.z >> 16);
                int c6 = (int)(iv.w & 0xffff), c7 = (int)(iv.w >> 16);
                float2 v0 = *(const float2*)&w1q[c0 * WST + chl];
                float2 v1 = *(const float2*)&w1q[c1 * WST + chl];
                float2 v2 = *(const float2*)&w1q[c2 * WST + chl];
                float2 v3 = *(const float2*)&w1q[c3 * WST + chl];
                float2 v4 = *(const float2*)&w1q[c4 * WST + chl];
                float2 v5 = *(const float2*)&w1q[c5 * WST + chl];
                float2 v6 = *(const float2*)&w1q[c6 * WST + chl];
                float2 v7 = *(const float2*)&w1q[c7 * WST + chl];
                // ordered ascending adds — do not reassociate (bit-exactness)
                a0 += v0.x; a1 += v0.y;
                a0 += v1.x; a1 += v1.y;
                a0 += v2.x; a1 += v2.y;
                a0 += v3.x; a1 += v3.y;
                a0 += v4.x; a1 += v4.y;
                a0 += v5.x; a1 += v5.y;
                a0 += v6.x; a1 += v6.y;
                a0 += v7.x; a1 += v7.y;
            }
            const int r = r0 + rl;
            const int b = r / TT;
            const int t = r - b * TT;
            *(float2*)&h[(size_t)t * (BB * HID) + (size_t)b * HID + q * QCH + chl] =
                make_float2(a0, a1);
        }
    }
}

// ---------------------------------------------------------------------------
// Kernel 2-fallback: round-3 spmm3 (global L2 gather), used if ws too small.
// ---------------------------------------------------------------------------
__global__ __launch_bounds__(256) void spmm3_kernel(const float* __restrict__ x,
                                                    const float* __restrict__ w1t,
                                                    float* __restrict__ h) {
    __shared__ ushort lists[4][144];
    const int lane = threadIdx.x & 63;
    const int w = threadIdx.x >> 6;
    const int r = blockIdx.x * 4 + w;
    const float* xrow = x + (size_t)r * ENC;
    const unsigned long long lt = (1ull << lane) - 1ull;

    float xv[11];
    #pragma unroll
    for (int k = 0; k < 11; ++k) {
        int c = k * 64 + lane;
        xv[k] = (c < ENC) ? xrow[c] : 0.0f;
    }
    int base = 0;
    #pragma unroll
    for (int k = 0; k < 11; ++k) {
        bool act = (xv[k] != 0.0f);
        unsigned long long m = __ballot(act);
        if (act) {
            int pos = base + (int)__popcll(m & lt);
            if (pos < 128) lists[w][pos] = (ushort)(k * 64 + lane);
        }
        base += (int)__popcll(m);
    }
    int n = (base < 128) ? base : 128;
    int npad = (n + 15) & ~15;
    if (lane < npad - n) lists[w][n + lane] = (ushort)ENC;
    __syncthreads();

    float accx = 0.f, accy = 0.f;
    for (int j = 0; j < npad; j += 16) {
        int c0  = lists[w][j + 0],  c1  = lists[w][j + 1];
        int c2  = lists[w][j + 2],  c3  = lists[w][j + 3];
        int c4  = lists[w][j + 4],  c5  = lists[w][j + 5];
        int c6  = lists[w][j + 6],  c7  = lists[w][j + 7];
        int c8  = lists[w][j + 8],  c9  = lists[w][j + 9];
        int c10 = lists[w][j + 10], c11 = lists[w][j + 11];
        int c12 = lists[w][j + 12], c13 = lists[w][j + 13];
        int c14 = lists[w][j + 14], c15 = lists[w][j + 15];
        float2 t0  = ((const float2*)(w1t + (size_t)c0  * HID))[lane];
        float2 t1  = ((const float2*)(w1t + (size_t)c1  * HID))[lane];
        float2 t2  = ((const float2*)(w1t + (size_t)c2  * HID))[lane];
        float2 t3  = ((const float2*)(w1t + (size_t)c3  * HID))[lane];
        float2 t4  = ((const float2*)(w1t + (size_t)c4  * HID))[lane];
        float2 t5  = ((const float2*)(w1t + (size_t)c5  * HID))[lane];
        float2 t6  = ((const float2*)(w1t + (size_t)c6  * HID))[lane];
        float2 t7  = ((const float2*)(w1t + (size_t)c7  * HID))[lane];
        float2 t8  = ((const float2*)(w1t + (size_t)c8  * HID))[lane];
        float2 t9  = ((const float2*)(w1t + (size_t)c9  * HID))[lane];
        float2 t10 = ((const float2*)(w1t + (size_t)c10 * HID))[lane];
        float2 t11 = ((const float2*)(w1t + (size_t)c11 * HID))[lane];
        float2 t12 = ((const float2*)(w1t + (size_t)c12 * HID))[lane];
        float2 t13 = ((const float2*)(w1t + (size_t)c13 * HID))[lane];
        float2 t14 = ((const float2*)(w1t + (size_t)c14 * HID))[lane];
        float2 t15 = ((const float2*)(w1t + (size_t)c15 * HID))[lane];
        accx += t0.x;  accy += t0.y;  accx += t1.x;  accy += t1.y;
        accx += t2.x;  accy += t2.y;  accx += t3.x;  accy += t3.y;
        accx += t4.x;  accy += t4.y;  accx += t5.x;  accy += t5.y;
        accx += t6.x;  accy += t6.y;  accx += t7.x;  accy += t7.y;
        accx += t8.x;  accy += t8.y;  accx += t9.x;  accy += t9.y;
        accx += t10.x; accy += t10.y; accx += t11.x; accy += t11.y;
        accx += t12.x; accy += t12.y; accx += t13.x; accy += t13.y;
        accx += t14.x; accy += t14.y; accx += t15.x; accy += t15.y;
    }
    int b = r / TT;
    int t = r - b * TT;
    float2* dst = (float2*)(h + (size_t)t * (BB * HID) + (size_t)b * HID);
    dst[lane] = make_float2(accx, accy);
}

// ---------------------------------------------------------------------------
// Kernel 3: temporal pipeline per b, v2. 128 threads (2 waves), 1 ch/lane.
// h chunk (50 t) prefetched into REGISTERS (13 float4/thread) during the
// previous chunk's scan, then ds_written to a single LDS buffer. No
// global_load_lds (avoids the all-LDS alias + vmcnt(0) poison).
// ---------------------------------------------------------------------------
__global__ __launch_bounds__(128) void recur2_kernel(const float* __restrict__ hgl,
                                                     const float* __restrict__ w2,
                                                     float* __restrict__ out) {
    __shared__ float hbuf[52 * 132];      // 27.5 KB, stride 132 (16B-aligned, rotated)
    __shared__ float vbuf[50 * 129];      // 25.8 KB
    __shared__ float pbuf[2][50];

    const int b = blockIdx.x;
    const int tid = threadIdx.x;          // 0..127 = channel

    const float D   = 0.95122942450071400910f;                                 // exp(-1/20)
    const float CD  = (float)(0.13591409142295226 * 0.95122942450071400910);   // (e/20)*d
    const float CRD = (float)(-0.27182818284590452 * 0.95122942450071400910);  // (-2e/20)*d

    float ap = 0.f, aq = 0.f, rp = 0.f, rq = 0.f;   // layer-1 state (ch = tid)
    float Ap = 0.f, Aq = 0.f, Rp = 0.f, Rq = 0.f;   // layer-2 state (redundant)
    const float w2v = w2[tid];

    const int tl0 = tid >> 5;             // 0..3: t-row within a load sweep
    const int ch0 = (tid & 31) * 4;       // float4 channel offset
    const float* hb = hgl + (size_t)b * HID + ch0;

    float4 pf[13];
    #pragma unroll
    for (int i = 0; i < 13; ++i) {        // prefetch chunk 0 (t = 0..51)
        int t = i * 4 + tl0;
        pf[i] = *(const float4*)(hb + (size_t)t * (BB * HID));
    }

    for (int chunk = 0; chunk < 10; ++chunk) {
        // 1. spill prefetched chunk to LDS
        #pragma unroll
        for (int i = 0; i < 13; ++i)
            *(float4*)&hbuf[(i * 4 + tl0) * 132 + ch0] = pf[i];
        __syncthreads();

        // 2. issue next chunk's loads (registers; consumed next iteration)
        {
            const int tb = (chunk + 1) * 50;
            #pragma unroll
            for (int i = 0; i < 13; ++i) {
                int t = tb + i * 4 + tl0;
                t = (t < TT) ? t : (TT - 1);          // clamp: harmless re-read
                pf[i] = *(const float4*)(hb + (size_t)t * (BB * HID));
            }
        }

        // 3. layer-1 scan, 50 steps
        #pragma unroll
        for (int tl = 0; tl < 50; ++tl) {
            float hv = hbuf[tl * 132 + tid];
            float y = fmaf(D, aq, CD * ap);
            aq = y;
            ap = fmaf(D, ap, hv);
            float q = fmaf(D, rq, CRD * rp);
            float u = y + q;
            float s = (u >= 1.0f) ? 1.0f : 0.0f;
            rq = q;
            rp = fmaf(D, rp, s);
            vbuf[tl * 129 + tid] = s * w2v;
        }
        __syncthreads();

        // 4. reduce o_t partials
        if (tid < 50) {
            const float* row = &vbuf[tid * 129];
            float a0 = 0.f, a1 = 0.f, a2 = 0.f, a3 = 0.f;
            #pragma unroll
            for (int k = 0; k < 64; k += 4) {
                a0 += row[k]; a1 += row[k + 1]; a2 += row[k + 2]; a3 += row[k + 3];
            }
            pbuf[0][tid] = (a0 + a1) + (a2 + a3);
        } else if (tid >= 64 && tid < 114) {
            const float* row = &vbuf[(tid - 64) * 129 + 64];
            float a0 = 0.f, a1 = 0.f, a2 = 0.f, a3 = 0.f;
            #pragma unroll
            for (int k = 0; k < 64; k += 4) {
                a0 += row[k]; a1 += row[k + 1]; a2 += row[k + 2]; a3 += row[k + 3];
            }
            pbuf[1][tid - 64] = (a0 + a1) + (a2 + a3);
        }
        __syncthreads();

        // 5. layer-2, 50 serial steps (redundant on all lanes)
        float my_s2 = 0.f;
        #pragma unroll
        for (int tl = 0; tl < 50; ++tl) {
            float ot = pbuf[0][tl] + pbuf[1][tl];
            float y2 = fmaf(D, Aq, CD * Ap);
            Aq = y2;
            Ap = fmaf(D, Ap, ot);
            float q2 = fmaf(D, Rq, CRD * Rp);
            float u2 = y2 + q2;
            float s2 = (u2 >= 1.0f) ? 1.0f : 0.0f;
            Rq = q2;
            Rp = fmaf(D, Rp, s2);
            if (tl == tid) my_s2 = s2;
        }
        if (tid < 50) out[(size_t)b * TT + chunk * 50 + tid] = my_s2;
        // hbuf rewrite next chunk is fenced by the step-1 barrier.
    }
}

// ---------------------------------------------------------------------------
extern "C" void kernel_launch(void* const* d_in, const int* in_sizes, int n_in,
                              void* d_out, int out_size, void* d_ws, size_t ws_size,
                              hipStream_t stream) {
    const float* x  = (const float*)d_in[0];   // (B, T, ENC) binary fp32
    const float* w1 = (const float*)d_in[1];   // (HID, ENC)
    const float* w2 = (const float*)d_in[2];   // (1, HID)
    float* out = (float*)d_out;                // (B, T, 1)

    // workspace layout
    const size_t H_ELEMS   = (size_t)TT * BB * HID;           // 16,384,000 floats
    const size_t W1T_ELEMS = (size_t)ENC_PAD * HID;           // 90,112 floats
    float* h   = (float*)d_ws;
    float* w1t = h + H_ELEMS;
    char* base2 = (char*)(w1t + W1T_ELEMS);                   // 65,896,448 B in
    ushort* lists = (ushort*)base2;                           // 20,480,000 B
    int* ncnt = (int*)(base2 + (size_t)BB * TT * LMAX * 2);   // 512,000 B
    const size_t NEED = (size_t)(base2 - (char*)d_ws) +
                        (size_t)BB * TT * LMAX * 2 + (size_t)BB * TT * 4;

    hipLaunchKernelGGL(transpose_w1_kernel, dim3(ENC_PAD), dim3(HID), 0, stream, w1, w1t);
    if (ws_size >= NEED) {
        hipLaunchKernelGGL(compress_kernel, dim3((BB * TT) / 4), dim3(256), 0, stream,
                           x, lists, ncnt);
        hipLaunchKernelGGL(gather_kernel, dim3(BB * TT / GROWS, HID / QCH), dim3(256),
                           0, stream, lists, ncnt, w1t, h);
    } else {
        hipLaunchKernelGGL(spmm3_kernel, dim3((BB * TT) / 4), dim3(256), 0, stream,
                           x, w1t, h);
    }
    hipLaunchKernelGGL(recur2_kernel, dim3(BB), dim3(128), 0, stream, h, w2, out);
}